// Round 1
// baseline (425.977 us; speedup 1.0000x reference)
//
#include <hip/hip_runtime.h>
#include <hip/hip_bf16.h>
#include <cstdint>

#define NSTR 4
#define CH 2048
#define NCF 8192          // NSTR * CH
#define NJ 24             // 4 pre + 4 post + 16 res
#define EPS_F 1e-5f
#define SINK_ITERS 20

// ---------------------------------------------------------------------------
// Prep: phiW[j][k] = bf16( alpha_j * w[k % CH] * phi_j[k] ),  j in [0,24)
// j 0..3 -> phi_pre rows, 4..7 -> phi_post rows, 8..23 -> phi_res rows
// ---------------------------------------------------------------------------
__global__ void __launch_bounds__(256) prep_phi_kernel(
    const float* __restrict__ w,
    const float* __restrict__ phi_pre,
    const float* __restrict__ phi_post,
    const float* __restrict__ phi_res,
    const float* __restrict__ alpha_pre,
    const float* __restrict__ alpha_post,
    const float* __restrict__ alpha_res,
    uint16_t* __restrict__ phiW)
{
    int idx = blockIdx.x * 256 + threadIdx.x;
    if (idx >= NJ * NCF) return;
    int j = idx / NCF;
    int k = idx - j * NCF;
    int c = k & (CH - 1);
    float v, a;
    if (j < 4)      { v = phi_pre[j * NCF + k];        a = alpha_pre[0]; }
    else if (j < 8) { v = phi_post[(j - 4) * NCF + k]; a = alpha_post[0]; }
    else            { v = phi_res[(j - 8) * NCF + k];  a = alpha_res[0]; }
    float f = v * a * w[c];
    __hip_bfloat16 h = __float2bfloat16(f);
    phiW[idx] = *reinterpret_cast<uint16_t*>(&h);
}

// ---------------------------------------------------------------------------
// Main fused kernel: one 256-thread block handles 2 batch rows.
// Thread t owns float4s at flat k = 4t + 1024*jj, jj = 0..7.
//   stream(k) = jj >> 1, channel quad cq = jj & 1 (c = 4t + 1024*cq)
// ---------------------------------------------------------------------------
__global__ void __launch_bounds__(256) mhc_main_kernel(
    const float* __restrict__ x,
    const uint16_t* __restrict__ phiW,
    const float* __restrict__ b_pre,
    const float* __restrict__ b_post,
    const float* __restrict__ b_res,
    float* __restrict__ out)
{
    const int t = threadIdx.x;
    const int lane = t & 63;
    const int wave = t >> 6;
    const long b0 = (long)blockIdx.x * 2;

    __shared__ float red[4][8];
    __shared__ float hred[4][48];
    __shared__ float H[2][24];

    // ---- load both x rows fully into registers (coalesced float4) ----
    float4 xv[2][8];
    const float4* xp0 = reinterpret_cast<const float4*>(x + b0 * NCF);
    const float4* xp1 = reinterpret_cast<const float4*>(x + (b0 + 1) * NCF);
    #pragma unroll
    for (int jj = 0; jj < 8; ++jj) {
        xv[0][jj] = xp0[t + 256 * jj];
        xv[1][jj] = xp1[t + 256 * jj];
    }

    // ---- RMS: sum of squares per (row, stream), block reduce ----
    float scl[2][4];
    {
        float ssp[8];
        #pragma unroll
        for (int r = 0; r < 2; ++r) {
            #pragma unroll
            for (int s = 0; s < 4; ++s) {
                float4 a = xv[r][2 * s], b = xv[r][2 * s + 1];
                ssp[r * 4 + s] = a.x * a.x + a.y * a.y + a.z * a.z + a.w * a.w
                               + b.x * b.x + b.y * b.y + b.z * b.z + b.w * b.w;
            }
        }
        #pragma unroll
        for (int i = 0; i < 8; ++i) {
            float v = ssp[i];
            #pragma unroll
            for (int m = 1; m < 64; m <<= 1) v += __shfl_xor(v, m, 64);
            if (lane == 0) red[wave][i] = v;
        }
        __syncthreads();
        #pragma unroll
        for (int i = 0; i < 8; ++i) {
            float ss = red[0][i] + red[1][i] + red[2][i] + red[3][i];
            scl[i >> 2][i & 3] = rsqrtf(ss * (1.0f / CH) + EPS_F);
        }
    }

    // ---- 24 projection dots, phi streamed as bf16, both rows per load ----
    float acc[2][NJ];
    #pragma unroll
    for (int j = 0; j < NJ; ++j) { acc[0][j] = 0.0f; acc[1][j] = 0.0f; }

    #pragma unroll
    for (int jj = 0; jj < 8; ++jj) {
        const int kbase = 4 * t + 1024 * jj;
        const float sA = scl[0][jj >> 1];
        const float sB = scl[1][jj >> 1];
        const float x0 = xv[0][jj].x * sA, x1 = xv[0][jj].y * sA,
                    x2 = xv[0][jj].z * sA, x3 = xv[0][jj].w * sA;
        const float y0 = xv[1][jj].x * sB, y1 = xv[1][jj].y * sB,
                    y2 = xv[1][jj].z * sB, y3 = xv[1][jj].w * sB;
        #pragma unroll
        for (int j = 0; j < NJ; ++j) {
            uint2 pv = *reinterpret_cast<const uint2*>(phiW + j * NCF + kbase);
            float p0 = __uint_as_float(pv.x << 16);
            float p1 = __uint_as_float(pv.x & 0xffff0000u);
            float p2 = __uint_as_float(pv.y << 16);
            float p3 = __uint_as_float(pv.y & 0xffff0000u);
            acc[0][j] = fmaf(x3, p3, fmaf(x2, p2, fmaf(x1, p1, fmaf(x0, p0, acc[0][j]))));
            acc[1][j] = fmaf(y3, p3, fmaf(y2, p2, fmaf(y1, p1, fmaf(y0, p0, acc[1][j]))));
        }
    }

    // ---- reduce 48 partial dots across the block ----
    #pragma unroll
    for (int j = 0; j < NJ; ++j) {
        float v0 = acc[0][j], v1 = acc[1][j];
        #pragma unroll
        for (int m = 1; m < 64; m <<= 1) {
            v0 += __shfl_xor(v0, m, 64);
            v1 += __shfl_xor(v1, m, 64);
        }
        if (lane == 0) { hred[wave][j] = v0; hred[wave][24 + j] = v1; }
    }
    __syncthreads();

    // ---- finalize h (add biases) ----
    if (t < 48) {
        int r = (t >= 24) ? 1 : 0;
        int j = t - 24 * r;
        float v = hred[0][t] + hred[1][t] + hred[2][t] + hred[3][t];
        float bias;
        if (j < 4)      bias = b_pre[j];
        else if (j < 8) bias = b_post[j - 4];
        else            bias = b_res[j - 8];
        H[r][j] = v + bias;
    }
    __syncthreads();

    // ---- Sinkhorn on 4x4 logits, 16 lanes per row (lanes 0..31) ----
    if (t < 32) {
        int r = t >> 4;
        int q = t & 15;          // q = i*4 + jx
        float L = H[r][8 + q];
        float mx = L;
        mx = fmaxf(mx, __shfl_xor(mx, 1, 64));
        mx = fmaxf(mx, __shfl_xor(mx, 2, 64));
        mx = fmaxf(mx, __shfl_xor(mx, 4, 64));
        mx = fmaxf(mx, __shfl_xor(mx, 8, 64));
        float m = __expf(L - mx);
        #pragma unroll
        for (int it = 0; it < SINK_ITERS; ++it) {
            float rs = m + __shfl_xor(m, 1, 64);
            rs += __shfl_xor(rs, 2, 64);
            m = m / (rs + EPS_F);           // row normalize (sum over jx)
            float cs = m + __shfl_xor(m, 4, 64);
            cs += __shfl_xor(cs, 8, 64);
            m = m / (cs + EPS_F);           // col normalize (sum over i)
        }
        H[r][8 + q] = m;
    }
    __syncthreads();

    // ---- mixing epilogue: out[i][c] = sum_j hres[i][j]*x[j][c] + hq[i]*agg[c]
    #pragma unroll
    for (int r = 0; r < 2; ++r) {
        float hp[4], hq[4], hrm[4][4];
        #pragma unroll
        for (int i = 0; i < 4; ++i) {
            hp[i] = H[r][i];
            hq[i] = H[r][4 + i];
            #pragma unroll
            for (int j = 0; j < 4; ++j) hrm[i][j] = H[r][8 + 4 * i + j];
        }
        float4* op = reinterpret_cast<float4*>(out + (b0 + r) * NCF);
        #pragma unroll
        for (int cq = 0; cq < 2; ++cq) {
            float4 s0 = xv[r][0 + cq], s1 = xv[r][2 + cq],
                   s2 = xv[r][4 + cq], s3 = xv[r][6 + cq];
            float ax = hp[0] * s0.x + hp[1] * s1.x + hp[2] * s2.x + hp[3] * s3.x;
            float ay = hp[0] * s0.y + hp[1] * s1.y + hp[2] * s2.y + hp[3] * s3.y;
            float az = hp[0] * s0.z + hp[1] * s1.z + hp[2] * s2.z + hp[3] * s3.z;
            float aw = hp[0] * s0.w + hp[1] * s1.w + hp[2] * s2.w + hp[3] * s3.w;
            #pragma unroll
            for (int i = 0; i < 4; ++i) {
                float4 o;
                o.x = hrm[i][0] * s0.x + hrm[i][1] * s1.x + hrm[i][2] * s2.x + hrm[i][3] * s3.x + hq[i] * ax;
                o.y = hrm[i][0] * s0.y + hrm[i][1] * s1.y + hrm[i][2] * s2.y + hrm[i][3] * s3.y + hq[i] * ay;
                o.z = hrm[i][0] * s0.z + hrm[i][1] * s1.z + hrm[i][2] * s2.z + hrm[i][3] * s3.z + hq[i] * az;
                o.w = hrm[i][0] * s0.w + hrm[i][1] * s1.w + hrm[i][2] * s2.w + hrm[i][3] * s3.w + hq[i] * aw;
                op[i * 512 + cq * 256 + t] = o;
            }
        }
    }
}

extern "C" void kernel_launch(void* const* d_in, const int* in_sizes, int n_in,
                              void* d_out, int out_size, void* d_ws, size_t ws_size,
                              hipStream_t stream)
{
    const float* x        = (const float*)d_in[0];
    const float* w        = (const float*)d_in[1];
    const float* phi_pre  = (const float*)d_in[2];
    const float* phi_post = (const float*)d_in[3];
    const float* phi_res  = (const float*)d_in[4];
    const float* b_pre    = (const float*)d_in[5];
    const float* b_post   = (const float*)d_in[6];
    const float* b_res    = (const float*)d_in[7];
    const float* a_pre    = (const float*)d_in[8];
    const float* a_post   = (const float*)d_in[9];
    const float* a_res    = (const float*)d_in[10];
    float* out = (float*)d_out;
    uint16_t* phiW = (uint16_t*)d_ws;   // NJ * NCF * 2 bytes = 384 KiB

    const int B = in_sizes[0] / NCF;    // 8192

    prep_phi_kernel<<<(NJ * NCF + 255) / 256, 256, 0, stream>>>(
        w, phi_pre, phi_post, phi_res, a_pre, a_post, a_res, phiW);

    mhc_main_kernel<<<B / 2, 256, 0, stream>>>(
        x, phiW, b_pre, b_post, b_res, out);
}